// Round 3
// baseline (40.187 us; speedup 1.0000x reference)
//
#include <hip/hip_runtime.h>

// LSP -> LPC, LPC_ORDER = 24, rows of 25 fp32: [K, ang0..ang23]
// P roots: ang[1::2]; Q roots: ang[0::2]
// Conjugate pair => real quadratic (x^2 - 2cos(th) x + 1); product of
// palindromic quadratics is palindromic: keep coeffs 0..12 only.
// Streaming 200MB (~2x L3) => non-temporal loads/stores (nt) to skip
// cache allocation. NOTE: __builtin_nontemporal_* needs a NATIVE clang
// vector type, not HIP_vector_type<float,4> (R2 compile failure).

typedef float f4 __attribute__((ext_vector_type(4)));

static constexpr int NC  = 25;
static constexpr int RPB = 256;                       // rows per block
static constexpr int FPB = NC * RPB;                  // 6400 floats per block
static constexpr int V4  = FPB / 4;                   // 1600 float4
static constexpr int TAIL = V4 - 6 * RPB;             // 64

__global__ __launch_bounds__(256)
void lsp2lpc_kernel(const float* __restrict__ in, float* __restrict__ out) {
    __shared__ float lds[FPB];                         // 25.6 KB -> 6 blocks/CU
    const int tid = threadIdx.x;
    const size_t base = (size_t)blockIdx.x * FPB;      // 25600 B, 16B-aligned

    // coalesced non-temporal f4 global -> LDS staging
    const f4* gin  = reinterpret_cast<const f4*>(in + base);
    f4*       lds4 = reinterpret_cast<f4*>(lds);
#pragma unroll
    for (int i = 0; i < 6; ++i)
        lds4[tid + i * RPB] = __builtin_nontemporal_load(&gin[tid + i * RPB]);
    if (tid < TAIL)
        lds4[tid + 6 * RPB] = __builtin_nontemporal_load(&gin[tid + 6 * RPB]);
    __syncthreads();

    // per-thread row (stride 25 = odd -> 2 lanes/bank, conflict-free)
    const float* row = &lds[tid * NC];
    const float K = row[0];
    float cp[12], cq[12];
#pragma unroll
    for (int m = 0; m < 12; ++m) {
        cq[m] = __cosf(row[1 + 2 * m]);   // Q: ang indices 0,2,..,22
        cp[m] = __cosf(row[2 + 2 * m]);   // P: ang indices 1,3,..,23
    }

    // palindromic lower halves of P, Q (degree 24 -> coeffs 0..12)
    float P[13], Q[13];
#pragma unroll
    for (int k = 0; k < 13; ++k) { P[k] = 0.f; Q[k] = 0.f; }
    P[0] = 1.f; Q[0] = 1.f;

#pragma unroll
    for (int m = 0; m < 12; ++m) {
        const float tp = -2.f * cp[m];
        const float tq = -2.f * cq[m];
        const int kmax = (2 * m + 2 < 12) ? (2 * m + 2) : 12;
#pragma unroll
        for (int k = 12; k >= 0; --k) {
            if (k > kmax) continue;               // compile-time pruned
            const float p1 = (k >= 1) ? P[k - 1] : 0.f;
            const float p2 = (k >= 2) ? P[k - 2] : 0.f;
            P[k] = fmaf(tp, p1, P[k]) + p2;
            const float q1 = (k >= 1) ? Q[k - 1] : 0.f;
            const float q2 = (k >= 2) ? Q[k - 2] : 0.f;
            Q[k] = fmaf(tq, q1, Q[k]) + q2;
        }
    }
    __syncthreads();   // all LDS input reads done; safe to overwrite buffer

    // epilogue: a[k] = 0.5*((Pf[k+1]-Pf[k]) + (Qf[k]+Qf[k+1])),
    // Pf[j] = j<=12 ? P[j] : P[24-j]
    float* orow = &lds[tid * NC];
    orow[0] = K;
#pragma unroll
    for (int k = 0; k < 24; ++k) {
        const int i0 = (k     <= 12) ? k       : 24 - k;
        const int i1 = (k + 1 <= 12) ? (k + 1) : 24 - (k + 1);
        const float pc = P[i1] - P[i0];
        const float qc = Q[i0] + Q[i1];
        orow[1 + k] = 0.5f * (pc + qc);
    }
    __syncthreads();

    // coalesced non-temporal f4 LDS -> global store
    f4* gout = reinterpret_cast<f4*>(out + base);
#pragma unroll
    for (int i = 0; i < 6; ++i)
        __builtin_nontemporal_store(lds4[tid + i * RPB], &gout[tid + i * RPB]);
    if (tid < TAIL)
        __builtin_nontemporal_store(lds4[tid + 6 * RPB], &gout[tid + 6 * RPB]);
}

extern "C" void kernel_launch(void* const* d_in, const int* in_sizes, int n_in,
                              void* d_out, int out_size, void* d_ws, size_t ws_size,
                              hipStream_t stream) {
    const float* in  = (const float*)d_in[0];
    float*       out = (float*)d_out;
    const int nrows   = in_sizes[0] / NC;   // 512*2048 = 1048576
    const int nblocks = nrows / RPB;        // 4096 (exact)
    lsp2lpc_kernel<<<nblocks, RPB, 0, stream>>>(in, out);
}

// Round 4
// 38.397 us; speedup vs baseline: 1.0466x; 1.0466x over previous
//
#include <hip/hip_runtime.h>

// LSP -> LPC, LPC_ORDER = 24, rows of 25 fp32: [K, ang0..ang23]
// P roots: ang[1::2]; Q roots: ang[0::2]
// Conjugate pair => real quadratic (x^2 - 2cos(th) x + 1); product of
// palindromic quadratics is palindromic: keep coeffs 0..12 only.
//
// Cache strategy (R3 post-mortem): in+out = 210MB < 256MB L3. Keep NORMAL
// loads so the read-only input becomes L3-resident across graph replays;
// use NON-TEMPORAL stores so the 105MB write stream doesn't allocate in L3
// and evict the input. Full-nt (R3) regressed: nt loads forfeit L3 reuse.

typedef float f4 __attribute__((ext_vector_type(4)));

static constexpr int NC  = 25;
static constexpr int RPB = 256;                       // rows per block
static constexpr int FPB = NC * RPB;                  // 6400 floats per block
static constexpr int V4  = FPB / 4;                   // 1600 float4
static constexpr int TAIL = V4 - 6 * RPB;             // 64

__global__ __launch_bounds__(256)
void lsp2lpc_kernel(const float* __restrict__ in, float* __restrict__ out) {
    __shared__ float lds[FPB];                         // 25.6 KB -> 6 blocks/CU
    const int tid = threadIdx.x;
    const size_t base = (size_t)blockIdx.x * FPB;      // 25600 B, 16B-aligned

    // coalesced f4 global -> LDS staging (normal loads: allocate in L3)
    const f4* gin  = reinterpret_cast<const f4*>(in + base);
    f4*       lds4 = reinterpret_cast<f4*>(lds);
#pragma unroll
    for (int i = 0; i < 6; ++i)
        lds4[tid + i * RPB] = gin[tid + i * RPB];
    if (tid < TAIL)
        lds4[tid + 6 * RPB] = gin[tid + 6 * RPB];
    __syncthreads();

    // per-thread row (stride 25 = odd -> 2 lanes/bank, conflict-free)
    const float* row = &lds[tid * NC];
    const float K = row[0];
    float cp[12], cq[12];
#pragma unroll
    for (int m = 0; m < 12; ++m) {
        cq[m] = __cosf(row[1 + 2 * m]);   // Q: ang indices 0,2,..,22
        cp[m] = __cosf(row[2 + 2 * m]);   // P: ang indices 1,3,..,23
    }

    // palindromic lower halves of P, Q (degree 24 -> coeffs 0..12)
    float P[13], Q[13];
#pragma unroll
    for (int k = 0; k < 13; ++k) { P[k] = 0.f; Q[k] = 0.f; }
    P[0] = 1.f; Q[0] = 1.f;

#pragma unroll
    for (int m = 0; m < 12; ++m) {
        const float tp = -2.f * cp[m];
        const float tq = -2.f * cq[m];
        const int kmax = (2 * m + 2 < 12) ? (2 * m + 2) : 12;
#pragma unroll
        for (int k = 12; k >= 0; --k) {
            if (k > kmax) continue;               // compile-time pruned
            const float p1 = (k >= 1) ? P[k - 1] : 0.f;
            const float p2 = (k >= 2) ? P[k - 2] : 0.f;
            P[k] = fmaf(tp, p1, P[k]) + p2;
            const float q1 = (k >= 1) ? Q[k - 1] : 0.f;
            const float q2 = (k >= 2) ? Q[k - 2] : 0.f;
            Q[k] = fmaf(tq, q1, Q[k]) + q2;
        }
    }
    __syncthreads();   // all LDS input reads done; safe to overwrite buffer

    // epilogue: a[k] = 0.5*((Pf[k+1]-Pf[k]) + (Qf[k]+Qf[k+1])),
    // Pf[j] = j<=12 ? P[j] : P[24-j]
    float* orow = &lds[tid * NC];
    orow[0] = K;
#pragma unroll
    for (int k = 0; k < 24; ++k) {
        const int i0 = (k     <= 12) ? k       : 24 - k;
        const int i1 = (k + 1 <= 12) ? (k + 1) : 24 - (k + 1);
        const float pc = P[i1] - P[i0];
        const float qc = Q[i0] + Q[i1];
        orow[1 + k] = 0.5f * (pc + qc);
    }
    __syncthreads();

    // coalesced f4 LDS -> global, NON-TEMPORAL (don't evict input from L3)
    f4* gout = reinterpret_cast<f4*>(out + base);
#pragma unroll
    for (int i = 0; i < 6; ++i)
        __builtin_nontemporal_store(lds4[tid + i * RPB], &gout[tid + i * RPB]);
    if (tid < TAIL)
        __builtin_nontemporal_store(lds4[tid + 6 * RPB], &gout[tid + 6 * RPB]);
}

extern "C" void kernel_launch(void* const* d_in, const int* in_sizes, int n_in,
                              void* d_out, int out_size, void* d_ws, size_t ws_size,
                              hipStream_t stream) {
    const float* in  = (const float*)d_in[0];
    float*       out = (float*)d_out;
    const int nrows   = in_sizes[0] / NC;   // 512*2048 = 1048576
    const int nblocks = nrows / RPB;        // 4096 (exact)
    lsp2lpc_kernel<<<nblocks, RPB, 0, stream>>>(in, out);
}

// Round 5
// 37.586 us; speedup vs baseline: 1.0692x; 1.0216x over previous
//
#include <hip/hip_runtime.h>

// LSP -> LPC, LPC_ORDER = 24, rows of 25 fp32: [K, ang0..ang23]
// P roots: ang[1::2]; Q roots: ang[0::2]
// Conjugate pair => real quadratic (x^2 - 2cos(th) x + 1); product of
// palindromic quadratics is palindromic: keep coeffs 0..12 only.
//
// R4 lesson: nt-store halved HBM fetch (L3-resident input) but time was
// flat -> not BW-bound at 38us. VALU (~13us/SIMD) + DS (~12us/CU) now
// co-limit. This round: P,Q packed as float2 -> v_pk_fma_f32 (CDNA4
// full-rate packed fp32) halves the polynomial-loop VALU.

typedef float f4 __attribute__((ext_vector_type(4)));
typedef float f2 __attribute__((ext_vector_type(2)));

static constexpr int NC  = 25;
static constexpr int RPB = 256;                       // rows per block
static constexpr int FPB = NC * RPB;                  // 6400 floats per block
static constexpr int V4  = FPB / 4;                   // 1600 float4
static constexpr int TAIL = V4 - 6 * RPB;             // 64

__global__ __launch_bounds__(256)
void lsp2lpc_kernel(const float* __restrict__ in, float* __restrict__ out) {
    __shared__ float lds[FPB];                         // 25.6 KB -> 6 blocks/CU
    const int tid = threadIdx.x;
    const size_t base = (size_t)blockIdx.x * FPB;      // 25600 B, 16B-aligned

    // coalesced f4 global -> LDS staging (normal loads: L3-resident input)
    const f4* gin  = reinterpret_cast<const f4*>(in + base);
    f4*       lds4 = reinterpret_cast<f4*>(lds);
#pragma unroll
    for (int i = 0; i < 6; ++i)
        lds4[tid + i * RPB] = gin[tid + i * RPB];
    if (tid < TAIL)
        lds4[tid + 6 * RPB] = gin[tid + 6 * RPB];
    __syncthreads();

    // per-thread row (stride 25 = odd -> 2 lanes/bank, conflict-free)
    const float* row = &lds[tid * NC];
    const float K = row[0];
    f2 t[12];                       // {tp, tq} per quadratic pair
#pragma unroll
    for (int m = 0; m < 12; ++m) {
        const float cq = __cosf(row[1 + 2 * m]);   // Q: ang idx 0,2,..,22
        const float cp = __cosf(row[2 + 2 * m]);   // P: ang idx 1,3,..,23
        t[m] = (f2){-2.f * cp, -2.f * cq};
    }

    // palindromic lower halves: PQ[k] = {P[k], Q[k]}, k = 0..12
    // packed recurrence -> v_pk_fma_f32 / v_pk_add_f32
    f2 PQ[13];
#pragma unroll
    for (int k = 0; k < 13; ++k) PQ[k] = (f2){0.f, 0.f};
    PQ[0] = (f2){1.f, 1.f};

#pragma unroll
    for (int m = 0; m < 12; ++m) {
        const f2 tm = t[m];
        const int kmax = (2 * m + 2 < 12) ? (2 * m + 2) : 12;
#pragma unroll
        for (int k = 12; k >= 0; --k) {
            if (k > kmax) continue;               // compile-time pruned
            const f2 c1 = (k >= 1) ? PQ[k - 1] : (f2){0.f, 0.f};
            const f2 c2 = (k >= 2) ? PQ[k - 2] : (f2){0.f, 0.f};
            PQ[k] = __builtin_elementwise_fma(tm, c1, PQ[k]) + c2;
        }
    }
    __syncthreads();   // all LDS input reads done; safe to overwrite buffer

    // a[k] = 0.5*(u[i1] + v[i0]);  u = P+Q, v = Q-P, palindromic fold
    float u[13], v[13];
#pragma unroll
    for (int k = 0; k < 13; ++k) {
        u[k] = PQ[k].x + PQ[k].y;
        v[k] = PQ[k].y - PQ[k].x;
    }
    float* orow = &lds[tid * NC];
    orow[0] = K;
#pragma unroll
    for (int k = 0; k < 24; ++k) {
        const int i0 = (k     <= 12) ? k       : 24 - k;
        const int i1 = (k + 1 <= 12) ? (k + 1) : 24 - (k + 1);
        orow[1 + k] = 0.5f * (u[i1] + v[i0]);
    }
    __syncthreads();

    // coalesced f4 LDS -> global, NON-TEMPORAL (don't evict input from L3)
    f4* gout = reinterpret_cast<f4*>(out + base);
#pragma unroll
    for (int i = 0; i < 6; ++i)
        __builtin_nontemporal_store(lds4[tid + i * RPB], &gout[tid + i * RPB]);
    if (tid < TAIL)
        __builtin_nontemporal_store(lds4[tid + 6 * RPB], &gout[tid + 6 * RPB]);
}

extern "C" void kernel_launch(void* const* d_in, const int* in_sizes, int n_in,
                              void* d_out, int out_size, void* d_ws, size_t ws_size,
                              hipStream_t stream) {
    const float* in  = (const float*)d_in[0];
    float*       out = (float*)d_out;
    const int nrows   = in_sizes[0] / NC;   // 512*2048 = 1048576
    const int nblocks = nrows / RPB;        // 4096 (exact)
    lsp2lpc_kernel<<<nblocks, RPB, 0, stream>>>(in, out);
}

// Round 6
// 37.337 us; speedup vs baseline: 1.0763x; 1.0067x over previous
//
#include <hip/hip_runtime.h>

// LSP -> LPC, LPC_ORDER = 24, rows of 25 fp32: [K, ang0..ang23]
// Conjugate-pair roots => real quadratics (x^2 - 2cos th x + 1); product of
// palindromic quadratics is palindromic: keep coeffs 0..12; P,Q packed as
// float2 -> v_pk_fma_f32 (R5). Normal loads (L3-resident input) +
// non-temporal stores (R4: halved HBM fetch).
//
// R6: persistent pipelined blocks. 1024 blocks x 4 tiles each; next tile's
// input prefetched to REGISTERS while computing current tile from LDS
// (T14 async-stage split) -> block-start load latency paid once per 4
// tiles, HBM latency hidden under compute.

typedef float f4 __attribute__((ext_vector_type(4)));
typedef float f2 __attribute__((ext_vector_type(2)));

static constexpr int NC   = 25;
static constexpr int RPB  = 256;                      // rows per tile
static constexpr int FPB  = NC * RPB;                 // 6400 floats per tile
static constexpr int V4   = FPB / 4;                  // 1600 float4
static constexpr int TAIL = V4 - 6 * RPB;             // 64
static constexpr int TPB_TILES = 4;                   // tiles per block

__device__ __forceinline__ void load_tile_regs(const float* __restrict__ in,
                                               int tile, int tid, f4* pf) {
    const f4* gin = reinterpret_cast<const f4*>(in + (size_t)tile * FPB);
#pragma unroll
    for (int i = 0; i < 6; ++i)
        pf[i] = gin[tid + i * RPB];
    pf[6] = (tid < TAIL) ? gin[tid + 6 * RPB] : (f4){0.f, 0.f, 0.f, 0.f};
}

__device__ __forceinline__ void write_regs_lds(f4* lds4, int tid, const f4* pf) {
#pragma unroll
    for (int i = 0; i < 6; ++i)
        lds4[tid + i * RPB] = pf[i];
    if (tid < TAIL)
        lds4[tid + 6 * RPB] = pf[6];
}

__global__ __launch_bounds__(256)
void lsp2lpc_kernel(const float* __restrict__ in, float* __restrict__ out) {
    __shared__ float lds[FPB];                        // 25.6 KB
    const int tid = threadIdx.x;
    f4* lds4 = reinterpret_cast<f4*>(lds);
    const int tile0 = blockIdx.x * TPB_TILES;

    // prologue: stage tile0
    f4 pf[7];
    load_tile_regs(in, tile0, tid, pf);
    write_regs_lds(lds4, tid, pf);
    __syncthreads();

    for (int t = 0; t < TPB_TILES; ++t) {
        const int tile = tile0 + t;

        // issue next tile's global loads early (latency hides under compute)
        if (t + 1 < TPB_TILES)
            load_tile_regs(in, tile + 1, tid, pf);

        // ---- compute current tile from LDS ----
        // per-thread row (stride 25 = odd -> 2 lanes/bank, conflict-free)
        const float* row = &lds[tid * NC];
        const float K = row[0];
        f2 tcoef[12];                                 // {tp, tq} per pair
#pragma unroll
        for (int m = 0; m < 12; ++m) {
            const float cq = __cosf(row[1 + 2 * m]); // Q: ang idx 0,2,..,22
            const float cp = __cosf(row[2 + 2 * m]); // P: ang idx 1,3,..,23
            tcoef[m] = (f2){-2.f * cp, -2.f * cq};
        }

        f2 PQ[13];                                    // {P[k], Q[k]}
#pragma unroll
        for (int k = 0; k < 13; ++k) PQ[k] = (f2){0.f, 0.f};
        PQ[0] = (f2){1.f, 1.f};

#pragma unroll
        for (int m = 0; m < 12; ++m) {
            const f2 tm = tcoef[m];
            const int kmax = (2 * m + 2 < 12) ? (2 * m + 2) : 12;
#pragma unroll
            for (int k = 12; k >= 0; --k) {
                if (k > kmax) continue;               // compile-time pruned
                const f2 c1 = (k >= 1) ? PQ[k - 1] : (f2){0.f, 0.f};
                const f2 c2 = (k >= 2) ? PQ[k - 2] : (f2){0.f, 0.f};
                PQ[k] = __builtin_elementwise_fma(tm, c1, PQ[k]) + c2;
            }
        }

        // epilogue into own row (no cross-thread hazard -> no barrier needed
        // between row reads above and these writes)
        float u[13], v[13];
#pragma unroll
        for (int k = 0; k < 13; ++k) {
            u[k] = PQ[k].x + PQ[k].y;                 // P+Q
            v[k] = PQ[k].y - PQ[k].x;                 // Q-P
        }
        float* orow = &lds[tid * NC];
        orow[0] = K;
#pragma unroll
        for (int k = 0; k < 24; ++k) {
            const int i0 = (k     <= 12) ? k       : 24 - k;
            const int i1 = (k + 1 <= 12) ? (k + 1) : 24 - (k + 1);
            orow[1 + k] = 0.5f * (u[i1] + v[i0]);
        }
        __syncthreads();    // outputs visible to cross-row f4 readers

        // coalesced f4 LDS -> global, NON-TEMPORAL (keep input in L3)
        f4* gout = reinterpret_cast<f4*>(out + (size_t)tile * FPB);
#pragma unroll
        for (int i = 0; i < 6; ++i)
            __builtin_nontemporal_store(lds4[tid + i * RPB], &gout[tid + i * RPB]);
        if (tid < TAIL)
            __builtin_nontemporal_store(lds4[tid + 6 * RPB], &gout[tid + 6 * RPB]);

        if (t + 1 < TPB_TILES) {
            __syncthreads();                 // all out-reads done before overwrite
            write_regs_lds(lds4, tid, pf);   // stage next tile (regs -> LDS)
            __syncthreads();                 // staged tile visible
        }
    }
}

extern "C" void kernel_launch(void* const* d_in, const int* in_sizes, int n_in,
                              void* d_out, int out_size, void* d_ws, size_t ws_size,
                              hipStream_t stream) {
    const float* in  = (const float*)d_in[0];
    float*       out = (float*)d_out;
    const int nrows   = in_sizes[0] / NC;             // 1048576
    const int ntiles  = nrows / RPB;                  // 4096
    const int nblocks = ntiles / TPB_TILES;           // 1024 (exact)
    lsp2lpc_kernel<<<nblocks, RPB, 0, stream>>>(in, out);
}